// Round 1
// baseline (155.931 us; speedup 1.0000x reference)
//
#include <hip/hip_runtime.h>
#include <math.h>

#define NDB 32
#define DMIN 0.5f
#define DMAX 15.0f
#define VV 4
#define CC 32
#define HH 128
#define WW 160
#define HWHW (HH*WW)
#define CONST_FLOATS 128

// ws float layout:
// [0..8]  Kinv of K_ref
// per view v (base = 16 + v*16): M[0..8] (= Rv^T Rref), b[9..11] (= Rv^T (t_ref - t_v)),
//                                fx=12, fy=13, cx=14, cy=15
__global__ void setup_consts(const float* __restrict__ K_ref,
                             const float* __restrict__ c2w_ref,
                             const float* __restrict__ K_srcs,
                             const float* __restrict__ c2w_srcs,
                             float* __restrict__ cw) {
    if (threadIdx.x != 0 || blockIdx.x != 0) return;
    // 3x3 inverse (adjugate) of K_ref
    float a00=K_ref[0], a01=K_ref[1], a02=K_ref[2];
    float a10=K_ref[3], a11=K_ref[4], a12=K_ref[5];
    float a20=K_ref[6], a21=K_ref[7], a22=K_ref[8];
    float det = a00*(a11*a22-a12*a21) - a01*(a10*a22-a12*a20) + a02*(a10*a21-a11*a20);
    float id = 1.0f/det;
    cw[0] = (a11*a22-a12*a21)*id;
    cw[1] = (a02*a21-a01*a22)*id;
    cw[2] = (a01*a12-a02*a11)*id;
    cw[3] = (a12*a20-a10*a22)*id;
    cw[4] = (a00*a22-a02*a20)*id;
    cw[5] = (a02*a10-a00*a12)*id;
    cw[6] = (a10*a21-a11*a20)*id;
    cw[7] = (a01*a20-a00*a21)*id;
    cw[8] = (a00*a11-a01*a10)*id;

    float Rr[9], tr[3];
    for (int i=0;i<3;i++){ for (int j=0;j<3;j++) Rr[i*3+j]=c2w_ref[i*4+j]; tr[i]=c2w_ref[i*4+3]; }

    for (int v=0; v<VV; v++) {
        const float* P = c2w_srcs + v*16;
        float Rv[9], tv[3];
        for (int i=0;i<3;i++){ for (int j=0;j<3;j++) Rv[i*3+j]=P[i*4+j]; tv[i]=P[i*4+3]; }
        float* o = cw + 16 + v*16;
        // M = Rv^T * Rr
        for (int i=0;i<3;i++) for (int j=0;j<3;j++) {
            float s = 0.f;
            for (int k=0;k<3;k++) s += Rv[k*3+i]*Rr[k*3+j];
            o[i*3+j] = s;
        }
        float dt0 = tr[0]-tv[0], dt1 = tr[1]-tv[1], dt2 = tr[2]-tv[2];
        for (int i=0;i<3;i++) {
            o[9+i] = Rv[0*3+i]*dt0 + Rv[1*3+i]*dt1 + Rv[2*3+i]*dt2;
        }
        const float* Ks = K_srcs + v*9;
        o[12]=Ks[0]; o[13]=Ks[4]; o[14]=Ks[2]; o[15]=Ks[5];
    }
}

// src_feats (V,C,HW) -> (V,HW,C)
__global__ __launch_bounds__(256) void transpose_src(const float* __restrict__ src,
                                                     float* __restrict__ dst) {
    int gid = blockIdx.x * 256 + threadIdx.x;
    if (gid >= VV*HWHW) return;
    int v = gid / HWHW, n = gid % HWHW;
    const float* in = src + (size_t)v*CC*HWHW + n;
    float4* outp = (float4*)(dst + (size_t)gid*CC);
    #pragma unroll
    for (int cc=0; cc<8; cc++) {
        float4 t;
        t.x = in[(size_t)(cc*4+0)*HWHW];
        t.y = in[(size_t)(cc*4+1)*HWHW];
        t.z = in[(size_t)(cc*4+2)*HWHW];
        t.w = in[(size_t)(cc*4+3)*HWHW];
        outp[cc] = t;
    }
}

// ref_feat (C,HW) -> normalized (HW,C)
__global__ __launch_bounds__(256) void ref_norm_t(const float* __restrict__ ref,
                                                  float* __restrict__ dst) {
    int n = blockIdx.x * 256 + threadIdx.x;
    if (n >= HWHW) return;
    float vals[CC];
    float ss = 0.f;
    #pragma unroll
    for (int c=0; c<CC; c++) { float x = ref[(size_t)c*HWHW + n]; vals[c]=x; ss += x*x; }
    float inv = 1.0f / fmaxf(sqrtf(ss), 1e-12f);
    float4* outp = (float4*)(dst + (size_t)n*CC);
    #pragma unroll
    for (int cc=0; cc<8; cc++) {
        outp[cc] = make_float4(vals[cc*4+0]*inv, vals[cc*4+1]*inv,
                               vals[cc*4+2]*inv, vals[cc*4+3]*inv);
    }
}

template<bool TRANS>
__global__ __launch_bounds__(256) void cost_volume_kernel(
        const float* __restrict__ srcp,  // TRANS: (V,HW,C) ; else (V,C,HW)
        const float* __restrict__ refp,  // TRANS: (HW,C) normalized ; else (C,HW) raw
        const float* __restrict__ cw,
        float* __restrict__ out) {
    int n = blockIdx.x * 256 + threadIdx.x;
    int d = blockIdx.y;
    if (n >= HWHW) return;
    float px = (float)(n % WW), py = (float)(n / WW);

    float rx = cw[0]*px + cw[1]*py + cw[2];
    float ry = cw[3]*px + cw[4]*py + cw[5];
    float rz = cw[6]*px + cw[7]*py + cw[8];

    const float invmin = 1.0f/DMAX;
    const float step = (1.0f/DMIN - 1.0f/DMAX) / (float)(NDB-1);
    float invd = invmin + step * (float)d;
    float depth = 1.0f / invd;

    float rf[CC];
    if (TRANS) {
        const float4* rp = (const float4*)(refp + (size_t)n*CC);
        #pragma unroll
        for (int cc=0; cc<8; cc++) {
            float4 t = rp[cc];
            rf[cc*4+0]=t.x; rf[cc*4+1]=t.y; rf[cc*4+2]=t.z; rf[cc*4+3]=t.w;
        }
    } else {
        float ss = 0.f;
        #pragma unroll
        for (int c=0; c<CC; c++) { float x = refp[(size_t)c*HWHW + n]; rf[c]=x; ss += x*x; }
        float inv = 1.0f / fmaxf(sqrtf(ss), 1e-12f);
        #pragma unroll
        for (int c=0; c<CC; c++) rf[c] *= inv;
    }

    float cost = 0.f;
    #pragma unroll
    for (int v=0; v<VV; v++) {
        const float* o = cw + 16 + v*16;
        float mx = o[0]*rx + o[1]*ry + o[2]*rz;
        float my = o[3]*rx + o[4]*ry + o[5]*rz;
        float mz = o[6]*rx + o[7]*ry + o[8]*rz;
        float X = depth*mx + o[9];
        float Y = depth*my + o[10];
        float Zraw = depth*mz + o[11];
        float Z = fmaxf(Zraw, 1e-6f);
        float u  = o[12]*(X/Z) + o[14];
        float vv = o[13]*(Y/Z) + o[15];
        float gx = 2.0f*(u/(float)(WW-1)) - 1.0f;
        float gy = 2.0f*(vv/(float)(HH-1)) - 1.0f;
        bool valid = (gx >= -1.0f) && (gx <= 1.0f) && (gy >= -1.0f) && (gy <= 1.0f) && (Zraw > 1e-6f);

        float x0f = floorf(u), y0f = floorf(vv);
        float wx1 = u - x0f,  wy1 = vv - y0f;
        float wx0 = 1.0f - wx1, wy0 = 1.0f - wy1;
        int x0 = (int)x0f, y0 = (int)y0f;
        int x1 = x0 + 1,   y1 = y0 + 1;

        float m00 = (x0>=0 && x0<WW && y0>=0 && y0<HH) ? 1.f : 0.f;
        float m10 = (x1>=0 && x1<WW && y0>=0 && y0<HH) ? 1.f : 0.f;
        float m01 = (x0>=0 && x0<WW && y1>=0 && y1<HH) ? 1.f : 0.f;
        float m11 = (x1>=0 && x1<WW && y1>=0 && y1<HH) ? 1.f : 0.f;
        float w00 = wx0*wy0*m00, w10 = wx1*wy0*m10;
        float w01 = wx0*wy1*m01, w11 = wx1*wy1*m11;

        int cx0 = min(max(x0,0),WW-1), cx1 = min(max(x1,0),WW-1);
        int cy0 = min(max(y0,0),HH-1), cy1 = min(max(y1,0),HH-1);
        int i00 = cy0*WW+cx0, i10 = cy0*WW+cx1;
        int i01 = cy1*WW+cx0, i11 = cy1*WW+cx1;

        float dot = 0.f, nrm = 0.f;
        if (TRANS) {
            const float4* p00 = (const float4*)(srcp + ((size_t)v*HWHW + i00)*CC);
            const float4* p10 = (const float4*)(srcp + ((size_t)v*HWHW + i10)*CC);
            const float4* p01 = (const float4*)(srcp + ((size_t)v*HWHW + i01)*CC);
            const float4* p11 = (const float4*)(srcp + ((size_t)v*HWHW + i11)*CC);
            #pragma unroll
            for (int cc=0; cc<8; cc++) {
                float4 g00=p00[cc], g10=p10[cc], g01=p01[cc], g11=p11[cc];
                float wa = w00*g00.x + w10*g10.x + w01*g01.x + w11*g11.x;
                float wb = w00*g00.y + w10*g10.y + w01*g01.y + w11*g11.y;
                float wc = w00*g00.z + w10*g10.z + w01*g01.z + w11*g11.z;
                float wd = w00*g00.w + w10*g10.w + w01*g01.w + w11*g11.w;
                dot += rf[cc*4+0]*wa + rf[cc*4+1]*wb + rf[cc*4+2]*wc + rf[cc*4+3]*wd;
                nrm += wa*wa + wb*wb + wc*wc + wd*wd;
            }
        } else {
            const float* basep = srcp + (size_t)v*CC*HWHW;
            #pragma unroll
            for (int c=0; c<CC; c++) {
                const float* pc = basep + (size_t)c*HWHW;
                float wcv = w00*pc[i00] + w10*pc[i10] + w01*pc[i01] + w11*pc[i11];
                dot += rf[c]*wcv;
                nrm += wcv*wcv;
            }
        }
        float sim = dot / fmaxf(sqrtf(nrm), 1e-12f);
        cost += valid ? sim : 0.f;
    }

    out[(size_t)d*HWHW + n] = cost * (1.0f/(float)VV);
    out[(size_t)NDB*HWHW + (size_t)d*HWHW + n] = depth;
}

extern "C" void kernel_launch(void* const* d_in, const int* in_sizes, int n_in,
                              void* d_out, int out_size, void* d_ws, size_t ws_size,
                              hipStream_t stream) {
    const float* ref_feat  = (const float*)d_in[0];
    const float* src_feats = (const float*)d_in[1];
    const float* K_ref     = (const float*)d_in[2];
    const float* c2w_ref   = (const float*)d_in[3];
    const float* K_srcs    = (const float*)d_in[4];
    const float* c2w_srcs  = (const float*)d_in[5];
    float* out = (float*)d_out;
    float* ws  = (float*)d_ws;

    setup_consts<<<1, 1, 0, stream>>>(K_ref, c2w_ref, K_srcs, c2w_srcs, ws);

    size_t need_bytes = (size_t)(CONST_FLOATS + (size_t)VV*HWHW*CC + (size_t)HWHW*CC) * sizeof(float);
    dim3 grid(HWHW/256, NDB);

    if (ws_size >= need_bytes) {
        float* srcT = ws + CONST_FLOATS;
        float* refT = srcT + (size_t)VV*HWHW*CC;
        transpose_src<<<(VV*HWHW + 255)/256, 256, 0, stream>>>(src_feats, srcT);
        ref_norm_t<<<(HWHW + 255)/256, 256, 0, stream>>>(ref_feat, refT);
        cost_volume_kernel<true><<<grid, 256, 0, stream>>>(srcT, refT, ws, out);
    } else {
        cost_volume_kernel<false><<<grid, 256, 0, stream>>>(src_feats, ref_feat, ws, out);
    }
}

// Round 2
// 75.907 us; speedup vs baseline: 2.0542x; 2.0542x over previous
//
#include <hip/hip_runtime.h>
#include <math.h>

#define NDB 32
#define DMIN 0.5f
#define DMAX 15.0f
#define VV 4
#define CC 32
#define HH 128
#define WW 160
#define HWHW (HH*WW)
#define CONST_FLOATS 128
#define NXCD 8

typedef _Float16 half8 __attribute__((ext_vector_type(8)));

// ws float layout:
// [0..8]  Kinv of K_ref
// per view v (base = 16 + v*16): M[0..8] (= Rv^T Rref), b[9..11] (= Rv^T (t_ref - t_v)),
//                                fx=12, fy=13, cx=14, cy=15
__global__ void setup_consts(const float* __restrict__ K_ref,
                             const float* __restrict__ c2w_ref,
                             const float* __restrict__ K_srcs,
                             const float* __restrict__ c2w_srcs,
                             float* __restrict__ cw) {
    if (threadIdx.x != 0 || blockIdx.x != 0) return;
    float a00=K_ref[0], a01=K_ref[1], a02=K_ref[2];
    float a10=K_ref[3], a11=K_ref[4], a12=K_ref[5];
    float a20=K_ref[6], a21=K_ref[7], a22=K_ref[8];
    float det = a00*(a11*a22-a12*a21) - a01*(a10*a22-a12*a20) + a02*(a10*a21-a11*a20);
    float id = 1.0f/det;
    cw[0] = (a11*a22-a12*a21)*id;
    cw[1] = (a02*a21-a01*a22)*id;
    cw[2] = (a01*a12-a02*a11)*id;
    cw[3] = (a12*a20-a10*a22)*id;
    cw[4] = (a00*a22-a02*a20)*id;
    cw[5] = (a02*a10-a00*a12)*id;
    cw[6] = (a10*a21-a11*a20)*id;
    cw[7] = (a01*a20-a00*a21)*id;
    cw[8] = (a00*a11-a01*a10)*id;

    float Rr[9], tr[3];
    for (int i=0;i<3;i++){ for (int j=0;j<3;j++) Rr[i*3+j]=c2w_ref[i*4+j]; tr[i]=c2w_ref[i*4+3]; }

    for (int v=0; v<VV; v++) {
        const float* P = c2w_srcs + v*16;
        float Rv[9], tv[3];
        for (int i=0;i<3;i++){ for (int j=0;j<3;j++) Rv[i*3+j]=P[i*4+j]; tv[i]=P[i*4+3]; }
        float* o = cw + 16 + v*16;
        for (int i=0;i<3;i++) for (int j=0;j<3;j++) {
            float s = 0.f;
            for (int k=0;k<3;k++) s += Rv[k*3+i]*Rr[k*3+j];
            o[i*3+j] = s;
        }
        float dt0 = tr[0]-tv[0], dt1 = tr[1]-tv[1], dt2 = tr[2]-tv[2];
        for (int i=0;i<3;i++) {
            o[9+i] = Rv[0*3+i]*dt0 + Rv[1*3+i]*dt1 + Rv[2*3+i]*dt2;
        }
        const float* Ks = K_srcs + v*9;
        o[12]=Ks[0]; o[13]=Ks[4]; o[14]=Ks[2]; o[15]=Ks[5];
    }
}

// src_feats (V,C,HW) f32 -> (V,HW,C) fp16
__global__ __launch_bounds__(256) void transpose_src_f16(const float* __restrict__ src,
                                                         _Float16* __restrict__ dst) {
    int gid = blockIdx.x * 256 + threadIdx.x;
    if (gid >= VV*HWHW) return;
    int v = gid / HWHW, n = gid % HWHW;
    const float* in = src + (size_t)v*CC*HWHW + n;
    half8* outp = (half8*)(dst + (size_t)gid*CC);
    #pragma unroll
    for (int cc=0; cc<4; cc++) {
        half8 t;
        #pragma unroll
        for (int j=0; j<8; j++)
            t[j] = (_Float16)in[(size_t)(cc*8+j)*HWHW];
        outp[cc] = t;
    }
}

// ref_feat (C,HW) f32 -> normalized (HW,C) fp16
__global__ __launch_bounds__(256) void ref_norm_t_f16(const float* __restrict__ ref,
                                                      _Float16* __restrict__ dst) {
    int n = blockIdx.x * 256 + threadIdx.x;
    if (n >= HWHW) return;
    float vals[CC];
    float ss = 0.f;
    #pragma unroll
    for (int c=0; c<CC; c++) { float x = ref[(size_t)c*HWHW + n]; vals[c]=x; ss += x*x; }
    float inv = 1.0f / fmaxf(sqrtf(ss), 1e-12f);
    half8* outp = (half8*)(dst + (size_t)n*CC);
    #pragma unroll
    for (int cc=0; cc<4; cc++) {
        half8 t;
        #pragma unroll
        for (int j=0; j<8; j++) t[j] = (_Float16)(vals[cc*8+j]*inv);
        outp[cc] = t;
    }
}

// Main kernel. 1D grid of (HWHW/256)*NDB blocks, XCD-locality swizzled:
//   b%8 selects XCD-group; within an XCD's block sequence, all 32 depths of a
//   pixel strip are consecutive -> per-XCD concurrent working set is a narrow
//   epipolar band, L2-resident.
__global__ __launch_bounds__(256) void cost_volume_f16(
        const _Float16* __restrict__ srcp,  // (V,HW,C) fp16
        const _Float16* __restrict__ refp,  // (HW,C) fp16 normalized
        const float* __restrict__ cw,
        float* __restrict__ out) {
    int b = blockIdx.x;
    int xcd = b & (NXCD-1);
    int t = b >> 3;           // 0..(NSTRIP*NDB/NXCD - 1)
    int d = t & (NDB-1);
    int sHigh = t >> 5;
    int s = xcd + NXCD*sHigh; // strip id, 0..79
    int n = s*256 + threadIdx.x;

    float px = (float)(n % WW), py = (float)(n / WW);

    float rx = cw[0]*px + cw[1]*py + cw[2];
    float ry = cw[3]*px + cw[4]*py + cw[5];
    float rz = cw[6]*px + cw[7]*py + cw[8];

    const float invmin = 1.0f/DMAX;
    const float step = (1.0f/DMIN - 1.0f/DMAX) / (float)(NDB-1);
    float invd = invmin + step * (float)d;
    float depth = 1.0f / invd;

    float rf[CC];
    {
        const half8* rp = (const half8*)(refp + (size_t)n*CC);
        #pragma unroll
        for (int cc=0; cc<4; cc++) {
            half8 t8 = rp[cc];
            #pragma unroll
            for (int j=0; j<8; j++) rf[cc*8+j] = (float)t8[j];
        }
    }

    // Per-view geometry first (so gathers from all views can be in flight).
    float w00a[VV], w10a[VV], w01a[VV], w11a[VV];
    int   i00a[VV], i10a[VV], i01a[VV], i11a[VV];
    bool  vld[VV];
    #pragma unroll
    for (int v=0; v<VV; v++) {
        const float* o = cw + 16 + v*16;
        float mx = o[0]*rx + o[1]*ry + o[2]*rz;
        float my = o[3]*rx + o[4]*ry + o[5]*rz;
        float mz = o[6]*rx + o[7]*ry + o[8]*rz;
        float X = depth*mx + o[9];
        float Y = depth*my + o[10];
        float Zraw = depth*mz + o[11];
        float Z = fmaxf(Zraw, 1e-6f);
        float u  = o[12]*(X/Z) + o[14];
        float vv = o[13]*(Y/Z) + o[15];
        float gx = 2.0f*(u/(float)(WW-1)) - 1.0f;
        float gy = 2.0f*(vv/(float)(HH-1)) - 1.0f;
        vld[v] = (gx >= -1.0f) && (gx <= 1.0f) && (gy >= -1.0f) && (gy <= 1.0f) && (Zraw > 1e-6f);

        float x0f = floorf(u), y0f = floorf(vv);
        float wx1 = u - x0f,  wy1 = vv - y0f;
        float wx0 = 1.0f - wx1, wy0 = 1.0f - wy1;
        int x0 = (int)x0f, y0 = (int)y0f;
        int x1 = x0 + 1,   y1 = y0 + 1;

        float m00 = (x0>=0 && x0<WW && y0>=0 && y0<HH) ? 1.f : 0.f;
        float m10 = (x1>=0 && x1<WW && y0>=0 && y0<HH) ? 1.f : 0.f;
        float m01 = (x0>=0 && x0<WW && y1>=0 && y1<HH) ? 1.f : 0.f;
        float m11 = (x1>=0 && x1<WW && y1>=0 && y1<HH) ? 1.f : 0.f;
        w00a[v] = wx0*wy0*m00; w10a[v] = wx1*wy0*m10;
        w01a[v] = wx0*wy1*m01; w11a[v] = wx1*wy1*m11;

        int cx0 = min(max(x0,0),WW-1), cx1 = min(max(x1,0),WW-1);
        int cy0 = min(max(y0,0),HH-1), cy1 = min(max(y1,0),HH-1);
        i00a[v] = cy0*WW+cx0; i10a[v] = cy0*WW+cx1;
        i01a[v] = cy1*WW+cx0; i11a[v] = cy1*WW+cx1;
    }

    float cost = 0.f;
    #pragma unroll
    for (int v=0; v<VV; v++) {
        const half8* p00 = (const half8*)(srcp + ((size_t)v*HWHW + i00a[v])*CC);
        const half8* p10 = (const half8*)(srcp + ((size_t)v*HWHW + i10a[v])*CC);
        const half8* p01 = (const half8*)(srcp + ((size_t)v*HWHW + i01a[v])*CC);
        const half8* p11 = (const half8*)(srcp + ((size_t)v*HWHW + i11a[v])*CC);
        float w00 = w00a[v], w10 = w10a[v], w01 = w01a[v], w11 = w11a[v];
        float dot = 0.f, nrm = 0.f;
        #pragma unroll
        for (int cc=0; cc<4; cc++) {
            half8 g00=p00[cc], g10=p10[cc], g01=p01[cc], g11=p11[cc];
            #pragma unroll
            for (int j=0; j<8; j++) {
                float wv_ = w00*(float)g00[j] + w10*(float)g10[j]
                          + w01*(float)g01[j] + w11*(float)g11[j];
                dot += rf[cc*8+j]*wv_;
                nrm += wv_*wv_;
            }
        }
        float sim = dot / fmaxf(sqrtf(nrm), 1e-12f);
        cost += vld[v] ? sim : 0.f;
    }

    out[(size_t)d*HWHW + n] = cost * (1.0f/(float)VV);
    out[(size_t)NDB*HWHW + (size_t)d*HWHW + n] = depth;
}

// f32 fallback (no workspace transposes): strided gathers from original layout.
__global__ __launch_bounds__(256) void cost_volume_fallback(
        const float* __restrict__ srcp,  // (V,C,HW)
        const float* __restrict__ refp,  // (C,HW)
        const float* __restrict__ cw,
        float* __restrict__ out) {
    int n = blockIdx.x * 256 + threadIdx.x;
    int d = blockIdx.y;
    if (n >= HWHW) return;
    float px = (float)(n % WW), py = (float)(n / WW);

    float rx = cw[0]*px + cw[1]*py + cw[2];
    float ry = cw[3]*px + cw[4]*py + cw[5];
    float rz = cw[6]*px + cw[7]*py + cw[8];

    const float invmin = 1.0f/DMAX;
    const float step = (1.0f/DMIN - 1.0f/DMAX) / (float)(NDB-1);
    float invd = invmin + step * (float)d;
    float depth = 1.0f / invd;

    float rf[CC];
    float ss = 0.f;
    #pragma unroll
    for (int c=0; c<CC; c++) { float x = refp[(size_t)c*HWHW + n]; rf[c]=x; ss += x*x; }
    float inv = 1.0f / fmaxf(sqrtf(ss), 1e-12f);
    #pragma unroll
    for (int c=0; c<CC; c++) rf[c] *= inv;

    float cost = 0.f;
    #pragma unroll
    for (int v=0; v<VV; v++) {
        const float* o = cw + 16 + v*16;
        float mx = o[0]*rx + o[1]*ry + o[2]*rz;
        float my = o[3]*rx + o[4]*ry + o[5]*rz;
        float mz = o[6]*rx + o[7]*ry + o[8]*rz;
        float X = depth*mx + o[9];
        float Y = depth*my + o[10];
        float Zraw = depth*mz + o[11];
        float Z = fmaxf(Zraw, 1e-6f);
        float u  = o[12]*(X/Z) + o[14];
        float vv = o[13]*(Y/Z) + o[15];
        float gx = 2.0f*(u/(float)(WW-1)) - 1.0f;
        float gy = 2.0f*(vv/(float)(HH-1)) - 1.0f;
        bool valid = (gx >= -1.0f) && (gx <= 1.0f) && (gy >= -1.0f) && (gy <= 1.0f) && (Zraw > 1e-6f);

        float x0f = floorf(u), y0f = floorf(vv);
        float wx1 = u - x0f,  wy1 = vv - y0f;
        float wx0 = 1.0f - wx1, wy0 = 1.0f - wy1;
        int x0 = (int)x0f, y0 = (int)y0f;
        int x1 = x0 + 1,   y1 = y0 + 1;

        float m00 = (x0>=0 && x0<WW && y0>=0 && y0<HH) ? 1.f : 0.f;
        float m10 = (x1>=0 && x1<WW && y0>=0 && y0<HH) ? 1.f : 0.f;
        float m01 = (x0>=0 && x0<WW && y1>=0 && y1<HH) ? 1.f : 0.f;
        float m11 = (x1>=0 && x1<WW && y1>=0 && y1<HH) ? 1.f : 0.f;
        float w00 = wx0*wy0*m00, w10 = wx1*wy0*m10;
        float w01 = wx0*wy1*m01, w11 = wx1*wy1*m11;

        int cx0 = min(max(x0,0),WW-1), cx1 = min(max(x1,0),WW-1);
        int cy0 = min(max(y0,0),HH-1), cy1 = min(max(y1,0),HH-1);
        int i00 = cy0*WW+cx0, i10 = cy0*WW+cx1;
        int i01 = cy1*WW+cx0, i11 = cy1*WW+cx1;

        float dot = 0.f, nrm = 0.f;
        const float* basep = srcp + (size_t)v*CC*HWHW;
        #pragma unroll
        for (int c=0; c<CC; c++) {
            const float* pc = basep + (size_t)c*HWHW;
            float wcv = w00*pc[i00] + w10*pc[i10] + w01*pc[i01] + w11*pc[i11];
            dot += rf[c]*wcv;
            nrm += wcv*wcv;
        }
        float sim = dot / fmaxf(sqrtf(nrm), 1e-12f);
        cost += valid ? sim : 0.f;
    }

    out[(size_t)d*HWHW + n] = cost * (1.0f/(float)VV);
    out[(size_t)NDB*HWHW + (size_t)d*HWHW + n] = depth;
}

extern "C" void kernel_launch(void* const* d_in, const int* in_sizes, int n_in,
                              void* d_out, int out_size, void* d_ws, size_t ws_size,
                              hipStream_t stream) {
    const float* ref_feat  = (const float*)d_in[0];
    const float* src_feats = (const float*)d_in[1];
    const float* K_ref     = (const float*)d_in[2];
    const float* c2w_ref   = (const float*)d_in[3];
    const float* K_srcs    = (const float*)d_in[4];
    const float* c2w_srcs  = (const float*)d_in[5];
    float* out = (float*)d_out;
    float* ws  = (float*)d_ws;

    setup_consts<<<1, 1, 0, stream>>>(K_ref, c2w_ref, K_srcs, c2w_srcs, ws);

    size_t need_bytes = (size_t)CONST_FLOATS*sizeof(float)
                      + (size_t)(VV+1)*HWHW*CC*sizeof(_Float16);

    if (ws_size >= need_bytes) {
        _Float16* srcT = (_Float16*)(ws + CONST_FLOATS);
        _Float16* refT = srcT + (size_t)VV*HWHW*CC;
        transpose_src_f16<<<(VV*HWHW + 255)/256, 256, 0, stream>>>(src_feats, srcT);
        ref_norm_t_f16<<<(HWHW + 255)/256, 256, 0, stream>>>(ref_feat, refT);
        cost_volume_f16<<<(HWHW/256)*NDB, 256, 0, stream>>>(srcT, refT, ws, out);
    } else {
        dim3 grid(HWHW/256, NDB);
        cost_volume_fallback<<<grid, 256, 0, stream>>>(src_feats, ref_feat, ws, out);
    }
}

// Round 3
// 52.236 us; speedup vs baseline: 2.9851x; 1.4532x over previous
//
#include <hip/hip_runtime.h>
#include <math.h>

#define NDB 32
#define DMIN 0.5f
#define DMAX 15.0f
#define VV 4
#define CC 32
#define HH 128
#define WW 160
#define HWHW (HH*WW)
#define CONST_FLOATS 128
#define NXCD 8

typedef _Float16 h8 __attribute__((ext_vector_type(8)));
typedef _Float16 h2 __attribute__((ext_vector_type(2)));

#if defined(__has_builtin)
#  if __has_builtin(__builtin_amdgcn_fdot2)
#    define FDOT2(a,b,c) __builtin_amdgcn_fdot2((a),(b),(c),false)
#  endif
#endif
#ifndef FDOT2
#  define FDOT2(a,b,c) ((c) + (float)(a)[0]*(float)(b)[0] + (float)(a)[1]*(float)(b)[1])
#endif

// ws float layout:
// [0..8]  Kinv of K_ref
// per view v (base = 16 + v*16): M[0..8] (= Rv^T Rref), b[9..11] (= Rv^T (t_ref - t_v)),
//                                fx=12, fy=13, cx=14, cy=15
__device__ __forceinline__ void do_setup(const float* __restrict__ K_ref,
                                         const float* __restrict__ c2w_ref,
                                         const float* __restrict__ K_srcs,
                                         const float* __restrict__ c2w_srcs,
                                         float* __restrict__ cw) {
    float a00=K_ref[0], a01=K_ref[1], a02=K_ref[2];
    float a10=K_ref[3], a11=K_ref[4], a12=K_ref[5];
    float a20=K_ref[6], a21=K_ref[7], a22=K_ref[8];
    float det = a00*(a11*a22-a12*a21) - a01*(a10*a22-a12*a20) + a02*(a10*a21-a11*a20);
    float id = 1.0f/det;
    cw[0] = (a11*a22-a12*a21)*id;
    cw[1] = (a02*a21-a01*a22)*id;
    cw[2] = (a01*a12-a02*a11)*id;
    cw[3] = (a12*a20-a10*a22)*id;
    cw[4] = (a00*a22-a02*a20)*id;
    cw[5] = (a02*a10-a00*a12)*id;
    cw[6] = (a10*a21-a11*a20)*id;
    cw[7] = (a01*a20-a00*a21)*id;
    cw[8] = (a00*a11-a01*a10)*id;

    float Rr[9], tr[3];
    for (int i=0;i<3;i++){ for (int j=0;j<3;j++) Rr[i*3+j]=c2w_ref[i*4+j]; tr[i]=c2w_ref[i*4+3]; }

    for (int v=0; v<VV; v++) {
        const float* P = c2w_srcs + v*16;
        float Rv[9], tv[3];
        for (int i=0;i<3;i++){ for (int j=0;j<3;j++) Rv[i*3+j]=P[i*4+j]; tv[i]=P[i*4+3]; }
        float* o = cw + 16 + v*16;
        for (int i=0;i<3;i++) for (int j=0;j<3;j++) {
            float s = 0.f;
            for (int k=0;k<3;k++) s += Rv[k*3+i]*Rr[k*3+j];
            o[i*3+j] = s;
        }
        float dt0 = tr[0]-tv[0], dt1 = tr[1]-tv[1], dt2 = tr[2]-tv[2];
        for (int i=0;i<3;i++) {
            o[9+i] = Rv[0*3+i]*dt0 + Rv[1*3+i]*dt1 + Rv[2*3+i]*dt2;
        }
        const float* Ks = K_srcs + v*9;
        o[12]=Ks[0]; o[13]=Ks[4]; o[14]=Ks[2]; o[15]=Ks[5];
    }
}

// Fused prepass: src transpose (V,C,HW)->(V,HW,C) fp16, ref normalize+transpose
// (C,HW)->(HW,C) fp16, and the tiny pose-composition setup on thread 0.
__global__ __launch_bounds__(256) void prepass(const float* __restrict__ src,
                                               const float* __restrict__ ref,
                                               const float* __restrict__ K_ref,
                                               const float* __restrict__ c2w_ref,
                                               const float* __restrict__ K_srcs,
                                               const float* __restrict__ c2w_srcs,
                                               _Float16* __restrict__ srcT,
                                               _Float16* __restrict__ refT,
                                               float* __restrict__ cw) {
    int gid = blockIdx.x * 256 + threadIdx.x;
    if (gid < VV*HWHW) {
        int v = gid / HWHW, n = gid % HWHW;
        const float* in = src + (size_t)v*CC*HWHW + n;
        h8* outp = (h8*)(srcT + (size_t)gid*CC);
        #pragma unroll
        for (int cc=0; cc<4; cc++) {
            h8 t;
            #pragma unroll
            for (int j=0; j<8; j++)
                t[j] = (_Float16)in[(size_t)(cc*8+j)*HWHW];
            outp[cc] = t;
        }
    } else if (gid < VV*HWHW + HWHW) {
        int n = gid - VV*HWHW;
        float vals[CC];
        float ss = 0.f;
        #pragma unroll
        for (int c=0; c<CC; c++) { float x = ref[(size_t)c*HWHW + n]; vals[c]=x; ss += x*x; }
        float inv = 1.0f / fmaxf(sqrtf(ss), 1e-12f);
        h8* outp = (h8*)(refT + (size_t)n*CC);
        #pragma unroll
        for (int cc=0; cc<4; cc++) {
            h8 t;
            #pragma unroll
            for (int j=0; j<8; j++) t[j] = (_Float16)(vals[cc*8+j]*inv);
            outp[cc] = t;
        }
    }
    if (gid == 0) do_setup(K_ref, c2w_ref, K_srcs, c2w_srcs, cw);
}

// Main kernel: 2 depths per thread. Grid = 80 strips * 16 depth-pairs, XCD-swizzled
// so each XCD works a fixed strip set across all depths (L2-resident epipolar band).
__global__ __launch_bounds__(256) void cost_volume_f16(
        const _Float16* __restrict__ srcp,  // (V,HW,C) fp16
        const _Float16* __restrict__ refp,  // (HW,C) fp16 normalized
        const float* __restrict__ cw,
        float* __restrict__ out) {
    int b = blockIdx.x;
    int xcd = b & (NXCD-1);
    int t = b >> 3;            // 0..159
    int dp = t & 15;           // depth pair id
    int sHigh = t >> 4;        // 0..9
    int s = xcd + NXCD*sHigh;  // strip 0..79
    int n = s*256 + threadIdx.x;

    // ref fragment (issued early)
    h8 rfv[4];
    {
        const h8* rp = (const h8*)(refp + (size_t)n*CC);
        #pragma unroll
        for (int cc=0; cc<4; cc++) rfv[cc] = rp[cc];
    }

    int ix = n % WW, iy = n / WW;
    float px = (float)ix, py = (float)iy;

    float rx = cw[0]*px + cw[1]*py + cw[2];
    float ry = cw[3]*px + cw[4]*py + cw[5];
    float rz = cw[6]*px + cw[7]*py + cw[8];

    // depth-independent per-view rotation of the ray
    float mxa[VV], mya[VV], mza[VV];
    #pragma unroll
    for (int v=0; v<VV; v++) {
        const float* o = cw + 16 + v*16;
        mxa[v] = o[0]*rx + o[1]*ry + o[2]*rz;
        mya[v] = o[3]*rx + o[4]*ry + o[5]*rz;
        mza[v] = o[6]*rx + o[7]*ry + o[8]*rz;
    }

    const float invmin = 1.0f/DMAX;
    const float step = (1.0f/DMIN - 1.0f/DMAX) / (float)(NDB-1);

    #pragma unroll
    for (int dd=0; dd<2; dd++) {
        int d = dp*2 + dd;
        float invd = invmin + step * (float)d;
        float depth = 1.0f / invd;

        float w00a[VV], w10a[VV], w01a[VV], w11a[VV];
        int   i00a[VV], i10a[VV], i01a[VV], i11a[VV];
        bool  vld[VV];
        #pragma unroll
        for (int v=0; v<VV; v++) {
            const float* o = cw + 16 + v*16;
            float X = depth*mxa[v] + o[9];
            float Y = depth*mya[v] + o[10];
            float Zraw = depth*mza[v] + o[11];
            float Z = fmaxf(Zraw, 1e-6f);
            float zr = 1.0f / Z;
            float u  = o[12]*(X*zr) + o[14];
            float vv = o[13]*(Y*zr) + o[15];
            float gx = 2.0f*(u/(float)(WW-1)) - 1.0f;
            float gy = 2.0f*(vv/(float)(HH-1)) - 1.0f;
            vld[v] = (gx >= -1.0f) && (gx <= 1.0f) && (gy >= -1.0f) && (gy <= 1.0f) && (Zraw > 1e-6f);

            float x0f = floorf(u), y0f = floorf(vv);
            float wx1 = u - x0f,  wy1 = vv - y0f;
            float wx0 = 1.0f - wx1, wy0 = 1.0f - wy1;
            int x0 = (int)x0f, y0 = (int)y0f;
            // Clamped corner indices. Out-of-range corners always carry zero
            // bilinear weight for valid samples; invalid samples are masked at
            // the end, so explicit corner masks are unnecessary.
            int cx0 = min(max(x0,0),WW-1),   cx1 = min(max(x0+1,0),WW-1);
            int cy0 = min(max(y0,0),HH-1),   cy1 = min(max(y0+1,0),HH-1);
            w00a[v] = wx0*wy0; w10a[v] = wx1*wy0;
            w01a[v] = wx0*wy1; w11a[v] = wx1*wy1;
            i00a[v] = cy0*WW+cx0; i10a[v] = cy0*WW+cx1;
            i01a[v] = cy1*WW+cx0; i11a[v] = cy1*WW+cx1;
        }

        float cost = 0.f;
        #pragma unroll
        for (int v=0; v<VV; v++) {
            const h8* p00 = (const h8*)(srcp + ((size_t)v*HWHW + i00a[v])*CC);
            const h8* p10 = (const h8*)(srcp + ((size_t)v*HWHW + i10a[v])*CC);
            const h8* p01 = (const h8*)(srcp + ((size_t)v*HWHW + i01a[v])*CC);
            const h8* p11 = (const h8*)(srcp + ((size_t)v*HWHW + i11a[v])*CC);
            _Float16 hw00 = (_Float16)w00a[v], hw10 = (_Float16)w10a[v];
            _Float16 hw01 = (_Float16)w01a[v], hw11 = (_Float16)w11a[v];
            h2 w00v = {hw00, hw00}, w10v = {hw10, hw10};
            h2 w01v = {hw01, hw01}, w11v = {hw11, hw11};
            float dot = 0.f, nrm = 0.f;
            #pragma unroll
            for (int cc=0; cc<4; cc++) {
                h8 g00=p00[cc], g10=p10[cc], g01=p01[cc], g11=p11[cc];
                #pragma unroll
                for (int i=0; i<4; i++) {
                    h2 a = (h2){g00[2*i],g00[2*i+1]} * w00v;
                    a += (h2){g10[2*i],g10[2*i+1]} * w10v;
                    a += (h2){g01[2*i],g01[2*i+1]} * w01v;
                    a += (h2){g11[2*i],g11[2*i+1]} * w11v;
                    h2 r = (h2){rfv[cc][2*i], rfv[cc][2*i+1]};
                    dot = FDOT2(r, a, dot);
                    nrm = FDOT2(a, a, nrm);
                }
            }
            float sim = dot * __builtin_amdgcn_rsqf(fmaxf(nrm, 1e-24f));
            cost += vld[v] ? sim : 0.f;
        }

        out[(size_t)d*HWHW + n] = cost * (1.0f/(float)VV);
        out[(size_t)NDB*HWHW + (size_t)d*HWHW + n] = depth;
    }
}

// f32 fallback (no workspace transposes): strided gathers from original layout.
__global__ __launch_bounds__(256) void cost_volume_fallback(
        const float* __restrict__ srcp,  // (V,C,HW)
        const float* __restrict__ refp,  // (C,HW)
        const float* __restrict__ cw,
        float* __restrict__ out) {
    int n = blockIdx.x * 256 + threadIdx.x;
    int d = blockIdx.y;
    if (n >= HWHW) return;
    float px = (float)(n % WW), py = (float)(n / WW);

    float rx = cw[0]*px + cw[1]*py + cw[2];
    float ry = cw[3]*px + cw[4]*py + cw[5];
    float rz = cw[6]*px + cw[7]*py + cw[8];

    const float invmin = 1.0f/DMAX;
    const float step = (1.0f/DMIN - 1.0f/DMAX) / (float)(NDB-1);
    float invd = invmin + step * (float)d;
    float depth = 1.0f / invd;

    float rf[CC];
    float ss = 0.f;
    #pragma unroll
    for (int c=0; c<CC; c++) { float x = refp[(size_t)c*HWHW + n]; rf[c]=x; ss += x*x; }
    float inv = 1.0f / fmaxf(sqrtf(ss), 1e-12f);
    #pragma unroll
    for (int c=0; c<CC; c++) rf[c] *= inv;

    float cost = 0.f;
    #pragma unroll
    for (int v=0; v<VV; v++) {
        const float* o = cw + 16 + v*16;
        float mx = o[0]*rx + o[1]*ry + o[2]*rz;
        float my = o[3]*rx + o[4]*ry + o[5]*rz;
        float mz = o[6]*rx + o[7]*ry + o[8]*rz;
        float X = depth*mx + o[9];
        float Y = depth*my + o[10];
        float Zraw = depth*mz + o[11];
        float Z = fmaxf(Zraw, 1e-6f);
        float u  = o[12]*(X/Z) + o[14];
        float vv = o[13]*(Y/Z) + o[15];
        float gx = 2.0f*(u/(float)(WW-1)) - 1.0f;
        float gy = 2.0f*(vv/(float)(HH-1)) - 1.0f;
        bool valid = (gx >= -1.0f) && (gx <= 1.0f) && (gy >= -1.0f) && (gy <= 1.0f) && (Zraw > 1e-6f);

        float x0f = floorf(u), y0f = floorf(vv);
        float wx1 = u - x0f,  wy1 = vv - y0f;
        float wx0 = 1.0f - wx1, wy0 = 1.0f - wy1;
        int x0 = (int)x0f, y0 = (int)y0f;
        int x1 = x0 + 1,   y1 = y0 + 1;

        float m00 = (x0>=0 && x0<WW && y0>=0 && y0<HH) ? 1.f : 0.f;
        float m10 = (x1>=0 && x1<WW && y0>=0 && y0<HH) ? 1.f : 0.f;
        float m01 = (x0>=0 && x0<WW && y1>=0 && y1<HH) ? 1.f : 0.f;
        float m11 = (x1>=0 && x1<WW && y1>=0 && y1<HH) ? 1.f : 0.f;
        float w00 = wx0*wy0*m00, w10 = wx1*wy0*m10;
        float w01 = wx0*wy1*m01, w11 = wx1*wy1*m11;

        int cx0 = min(max(x0,0),WW-1), cx1 = min(max(x1,0),WW-1);
        int cy0 = min(max(y0,0),HH-1), cy1 = min(max(y1,0),HH-1);
        int i00 = cy0*WW+cx0, i10 = cy0*WW+cx1;
        int i01 = cy1*WW+cx0, i11 = cy1*WW+cx1;

        float dot = 0.f, nrm = 0.f;
        const float* basep = srcp + (size_t)v*CC*HWHW;
        #pragma unroll
        for (int c=0; c<CC; c++) {
            const float* pc = basep + (size_t)c*HWHW;
            float wcv = w00*pc[i00] + w10*pc[i10] + w01*pc[i01] + w11*pc[i11];
            dot += rf[c]*wcv;
            nrm += wcv*wcv;
        }
        float sim = dot / fmaxf(sqrtf(nrm), 1e-12f);
        cost += valid ? sim : 0.f;
    }

    out[(size_t)d*HWHW + n] = cost * (1.0f/(float)VV);
    out[(size_t)NDB*HWHW + (size_t)d*HWHW + n] = depth;
}

extern "C" void kernel_launch(void* const* d_in, const int* in_sizes, int n_in,
                              void* d_out, int out_size, void* d_ws, size_t ws_size,
                              hipStream_t stream) {
    const float* ref_feat  = (const float*)d_in[0];
    const float* src_feats = (const float*)d_in[1];
    const float* K_ref     = (const float*)d_in[2];
    const float* c2w_ref   = (const float*)d_in[3];
    const float* K_srcs    = (const float*)d_in[4];
    const float* c2w_srcs  = (const float*)d_in[5];
    float* out = (float*)d_out;
    float* ws  = (float*)d_ws;

    size_t need_bytes = (size_t)CONST_FLOATS*sizeof(float)
                      + (size_t)(VV+1)*HWHW*CC*sizeof(_Float16);

    if (ws_size >= need_bytes) {
        _Float16* srcT = (_Float16*)(ws + CONST_FLOATS);
        _Float16* refT = srcT + (size_t)VV*HWHW*CC;
        prepass<<<((VV+1)*HWHW + 255)/256, 256, 0, stream>>>(
            src_feats, ref_feat, K_ref, c2w_ref, K_srcs, c2w_srcs, srcT, refT, ws);
        cost_volume_f16<<<(HWHW/256)*(NDB/2), 256, 0, stream>>>(srcT, refT, ws, out);
    } else {
        // tiny setup on one thread via prepass-equivalent path is unavailable;
        // reuse fallback: compute consts with a 1-thread launch of prepass over 0 work
        prepass<<<1, 256, 0, stream>>>(
            src_feats, ref_feat, K_ref, c2w_ref, K_srcs, c2w_srcs,
            (_Float16*)ws, (_Float16*)ws, ws);  // only gid==0 setup matters here
        dim3 grid(HWHW/256, NDB);
        cost_volume_fallback<<<grid, 256, 0, stream>>>(src_feats, ref_feat, ws, out);
    }
}

// Round 4
// 42.593 us; speedup vs baseline: 3.6609x; 1.2264x over previous
//
#include <hip/hip_runtime.h>
#include <math.h>

#define NDB 32
#define DMIN 0.5f
#define DMAX 15.0f
#define VV 4
#define CC 32
#define HH 128
#define WW 160
#define HWHW (HH*WW)
#define CONST_FLOATS 128
#define NXCD 8

typedef _Float16 h8 __attribute__((ext_vector_type(8)));
typedef _Float16 h2 __attribute__((ext_vector_type(2)));

#if defined(__has_builtin)
#  if __has_builtin(__builtin_amdgcn_fdot2)
#    define FDOT2(a,b,c) __builtin_amdgcn_fdot2((a),(b),(c),false)
#  endif
#endif
#ifndef FDOT2
#  define FDOT2(a,b,c) ((c) + (float)(a)[0]*(float)(b)[0] + (float)(a)[1]*(float)(b)[1])
#endif

// ws float layout:
// [0..8]  Kinv of K_ref
// per view v (base = 16 + v*16): M[0..8] (= Rv^T Rref), b[9..11] (= Rv^T (t_ref - t_v)),
//                                fx=12, fy=13, cx=14, cy=15
__device__ __forceinline__ void do_setup(const float* __restrict__ K_ref,
                                         const float* __restrict__ c2w_ref,
                                         const float* __restrict__ K_srcs,
                                         const float* __restrict__ c2w_srcs,
                                         float* __restrict__ cw) {
    float a00=K_ref[0], a01=K_ref[1], a02=K_ref[2];
    float a10=K_ref[3], a11=K_ref[4], a12=K_ref[5];
    float a20=K_ref[6], a21=K_ref[7], a22=K_ref[8];
    float det = a00*(a11*a22-a12*a21) - a01*(a10*a22-a12*a20) + a02*(a10*a21-a11*a20);
    float id = 1.0f/det;
    cw[0] = (a11*a22-a12*a21)*id;
    cw[1] = (a02*a21-a01*a22)*id;
    cw[2] = (a01*a12-a02*a11)*id;
    cw[3] = (a12*a20-a10*a22)*id;
    cw[4] = (a00*a22-a02*a20)*id;
    cw[5] = (a02*a10-a00*a12)*id;
    cw[6] = (a10*a21-a11*a20)*id;
    cw[7] = (a01*a20-a00*a21)*id;
    cw[8] = (a00*a11-a01*a10)*id;

    float Rr[9], tr[3];
    for (int i=0;i<3;i++){ for (int j=0;j<3;j++) Rr[i*3+j]=c2w_ref[i*4+j]; tr[i]=c2w_ref[i*4+3]; }

    for (int v=0; v<VV; v++) {
        const float* P = c2w_srcs + v*16;
        float Rv[9], tv[3];
        for (int i=0;i<3;i++){ for (int j=0;j<3;j++) Rv[i*3+j]=P[i*4+j]; tv[i]=P[i*4+3]; }
        float* o = cw + 16 + v*16;
        for (int i=0;i<3;i++) for (int j=0;j<3;j++) {
            float s = 0.f;
            for (int k=0;k<3;k++) s += Rv[k*3+i]*Rr[k*3+j];
            o[i*3+j] = s;
        }
        float dt0 = tr[0]-tv[0], dt1 = tr[1]-tv[1], dt2 = tr[2]-tv[2];
        for (int i=0;i<3;i++) {
            o[9+i] = Rv[0*3+i]*dt0 + Rv[1*3+i]*dt1 + Rv[2*3+i]*dt2;
        }
        const float* Ks = K_srcs + v*9;
        o[12]=Ks[0]; o[13]=Ks[4]; o[14]=Ks[2]; o[15]=Ks[5];
    }
}

// Fused prepass: src transpose (V,C,HW)->(V,HW,C) fp16, ref normalize+transpose,
// pose setup (thread 0), AND the depth_planes output (coalesced f32 writes).
__global__ __launch_bounds__(256) void prepass(const float* __restrict__ src,
                                               const float* __restrict__ ref,
                                               const float* __restrict__ K_ref,
                                               const float* __restrict__ c2w_ref,
                                               const float* __restrict__ K_srcs,
                                               const float* __restrict__ c2w_srcs,
                                               _Float16* __restrict__ srcT,
                                               _Float16* __restrict__ refT,
                                               float* __restrict__ cw,
                                               float* __restrict__ out) {
    int gid = blockIdx.x * 256 + threadIdx.x;
    const float invmin = 1.0f/DMAX;
    const float step = (1.0f/DMIN - 1.0f/DMAX) / (float)(NDB-1);
    if (gid < VV*HWHW) {
        int v = gid / HWHW, n = gid % HWHW;
        const float* in = src + (size_t)v*CC*HWHW + n;
        h8* outp = (h8*)(srcT + (size_t)gid*CC);
        #pragma unroll
        for (int cc=0; cc<4; cc++) {
            h8 t;
            #pragma unroll
            for (int j=0; j<8; j++)
                t[j] = (_Float16)in[(size_t)(cc*8+j)*HWHW];
            outp[cc] = t;
        }
    } else if (gid < (VV+1)*HWHW) {
        int n = gid - VV*HWHW;
        float vals[CC];
        float ss = 0.f;
        #pragma unroll
        for (int c=0; c<CC; c++) { float x = ref[(size_t)c*HWHW + n]; vals[c]=x; ss += x*x; }
        float inv = 1.0f / fmaxf(sqrtf(ss), 1e-12f);
        h8* outp = (h8*)(refT + (size_t)n*CC);
        #pragma unroll
        for (int cc=0; cc<4; cc++) {
            h8 t;
            #pragma unroll
            for (int j=0; j<8; j++) t[j] = (_Float16)(vals[cc*8+j]*inv);
            outp[cc] = t;
        }
    } else if (gid < (VV+1)*HWHW + NDB*HWHW) {
        int i = gid - (VV+1)*HWHW;
        int d = i / HWHW;
        out[(size_t)NDB*HWHW + i] = 1.0f / (invmin + step*(float)d);
    }
    if (gid == 0) do_setup(K_ref, c2w_ref, K_srcs, c2w_srcs, cw);
}

// Main kernel: QUAD-per-pixel. 4 lanes own one pixel; lane j holds channels
// [8j..8j+8). Corner loads from the (HW,C) fp16 layout are 4 contiguous 16B
// chunks per 64B pixel line -> coalesce to ONE line transaction per corner
// (vs 4 in the thread-per-pixel layout). Dot/norm quad-reduced via shfl_xor.
// 2 depths per thread. XCD-swizzled strips of 64 pixels.
__global__ __launch_bounds__(256) void cost_volume_quad(
        const _Float16* __restrict__ srcp,  // (V,HW,C) fp16
        const _Float16* __restrict__ refp,  // (HW,C) fp16 normalized
        const float* __restrict__ cw,
        float* __restrict__ out) {
    int b = blockIdx.x;
    int xcd = b & (NXCD-1);
    int t = b >> 3;            // 0..639
    int dp = t & 15;           // depth-pair id 0..15
    int sHigh = t >> 4;        // 0..39
    int s = xcd + NXCD*sHigh;  // strip 0..319 (64 pixels each)
    int j = threadIdx.x & 3;   // chunk id within pixel
    int q = threadIdx.x >> 2;  // pixel within strip
    int n = s*64 + q;

    // this lane's ref chunk (8 channels, 16B, quad-contiguous -> coalesced)
    h8 rfv = *(const h8*)(refp + (size_t)n*CC + j*8);

    int ix = n % WW, iy = n / WW;
    float px = (float)ix, py = (float)iy;

    float rx = cw[0]*px + cw[1]*py + cw[2];
    float ry = cw[3]*px + cw[4]*py + cw[5];
    float rz = cw[6]*px + cw[7]*py + cw[8];

    // depth-independent per-view ray rotation
    float mxa[VV], mya[VV], mza[VV];
    #pragma unroll
    for (int v=0; v<VV; v++) {
        const float* o = cw + 16 + v*16;
        mxa[v] = o[0]*rx + o[1]*ry + o[2]*rz;
        mya[v] = o[3]*rx + o[4]*ry + o[5]*rz;
        mza[v] = o[6]*rx + o[7]*ry + o[8]*rz;
    }

    const float invmin = 1.0f/DMAX;
    const float step = (1.0f/DMIN - 1.0f/DMAX) / (float)(NDB-1);

    #pragma unroll
    for (int dd=0; dd<2; dd++) {
        int d = dp*2 + dd;
        float invd = invmin + step * (float)d;
        float zthr = 1e-6f * invd;   // Zraw>1e-6  <=>  az>zthr (az = Zraw*invd)

        float cost = 0.f;
        #pragma unroll
        for (int v=0; v<VV; v++) {
            const float* o = cw + 16 + v*16;
            // projective form: u = fx*(ax/az)+cx with ax = mx + bx*invd (a* = X*invd)
            float ax = fmaf(o[9],  invd, mxa[v]);
            float ay = fmaf(o[10], invd, mya[v]);
            float az = fmaf(o[11], invd, mza[v]);
            float azc = fmaxf(az, zthr);
            float zr = __builtin_amdgcn_rcpf(azc);
            float u  = fmaf(o[12], ax*zr, o[14]);
            float vv = fmaf(o[13], ay*zr, o[15]);
            bool vld = (u >= 0.0f) && (u <= (float)(WW-1)) &&
                       (vv >= 0.0f) && (vv <= (float)(HH-1)) && (az > zthr);

            float x0f = floorf(u), y0f = floorf(vv);
            float wx1 = u - x0f,  wy1 = vv - y0f;
            float wx0 = 1.0f - wx1, wy0 = 1.0f - wy1;
            int x0 = (int)x0f, y0 = (int)y0f;
            int cx0 = min(max(x0,0),WW-1),   cx1 = min(max(x0+1,0),WW-1);
            int cy0 = min(max(y0,0),HH-1),   cy1 = min(max(y0+1,0),HH-1);
            int i00 = cy0*WW+cx0, i10 = cy0*WW+cx1;
            int i01 = cy1*WW+cx0, i11 = cy1*WW+cx1;

            const _Float16* bv = srcp + (size_t)v*HWHW*CC + j*8;
            h8 g00 = *(const h8*)(bv + (size_t)i00*CC);
            h8 g10 = *(const h8*)(bv + (size_t)i10*CC);
            h8 g01 = *(const h8*)(bv + (size_t)i01*CC);
            h8 g11 = *(const h8*)(bv + (size_t)i11*CC);

            _Float16 hw00 = (_Float16)(wx0*wy0), hw10 = (_Float16)(wx1*wy0);
            _Float16 hw01 = (_Float16)(wx0*wy1), hw11 = (_Float16)(wx1*wy1);
            h2 w00v = {hw00, hw00}, w10v = {hw10, hw10};
            h2 w01v = {hw01, hw01}, w11v = {hw11, hw11};

            float dt = 0.f, nm = 0.f;
            #pragma unroll
            for (int i=0; i<4; i++) {
                h2 a = (h2){g00[2*i],g00[2*i+1]} * w00v;
                a += (h2){g10[2*i],g10[2*i+1]} * w10v;
                a += (h2){g01[2*i],g01[2*i+1]} * w01v;
                a += (h2){g11[2*i],g11[2*i+1]} * w11v;
                h2 r = (h2){rfv[2*i], rfv[2*i+1]};
                dt = FDOT2(r, a, dt);
                nm = FDOT2(a, a, nm);
            }
            // quad reduction (lanes j^1, j^2 are the same pixel)
            dt += __shfl_xor(dt, 1); dt += __shfl_xor(dt, 2);
            nm += __shfl_xor(nm, 1); nm += __shfl_xor(nm, 2);

            float sim = dt * __builtin_amdgcn_rsqf(fmaxf(nm, 1e-24f));
            cost += vld ? sim : 0.f;
        }
        if (j == 0) out[(size_t)d*HWHW + n] = cost * (1.0f/(float)VV);
    }
}

// f32 fallback (no workspace): strided gathers from original layout.
__global__ __launch_bounds__(256) void cost_volume_fallback(
        const float* __restrict__ srcp,  // (V,C,HW)
        const float* __restrict__ refp,  // (C,HW)
        const float* __restrict__ cw,
        float* __restrict__ out) {
    int n = blockIdx.x * 256 + threadIdx.x;
    int d = blockIdx.y;
    if (n >= HWHW) return;
    float px = (float)(n % WW), py = (float)(n / WW);

    float rx = cw[0]*px + cw[1]*py + cw[2];
    float ry = cw[3]*px + cw[4]*py + cw[5];
    float rz = cw[6]*px + cw[7]*py + cw[8];

    const float invmin = 1.0f/DMAX;
    const float step = (1.0f/DMIN - 1.0f/DMAX) / (float)(NDB-1);
    float invd = invmin + step * (float)d;
    float depth = 1.0f / invd;

    float rf[CC];
    float ss = 0.f;
    #pragma unroll
    for (int c=0; c<CC; c++) { float x = refp[(size_t)c*HWHW + n]; rf[c]=x; ss += x*x; }
    float inv = 1.0f / fmaxf(sqrtf(ss), 1e-12f);
    #pragma unroll
    for (int c=0; c<CC; c++) rf[c] *= inv;

    float cost = 0.f;
    #pragma unroll
    for (int v=0; v<VV; v++) {
        const float* o = cw + 16 + v*16;
        float mx = o[0]*rx + o[1]*ry + o[2]*rz;
        float my = o[3]*rx + o[4]*ry + o[5]*rz;
        float mz = o[6]*rx + o[7]*ry + o[8]*rz;
        float X = depth*mx + o[9];
        float Y = depth*my + o[10];
        float Zraw = depth*mz + o[11];
        float Z = fmaxf(Zraw, 1e-6f);
        float u  = o[12]*(X/Z) + o[14];
        float vv = o[13]*(Y/Z) + o[15];
        float gx = 2.0f*(u/(float)(WW-1)) - 1.0f;
        float gy = 2.0f*(vv/(float)(HH-1)) - 1.0f;
        bool valid = (gx >= -1.0f) && (gx <= 1.0f) && (gy >= -1.0f) && (gy <= 1.0f) && (Zraw > 1e-6f);

        float x0f = floorf(u), y0f = floorf(vv);
        float wx1 = u - x0f,  wy1 = vv - y0f;
        float wx0 = 1.0f - wx1, wy0 = 1.0f - wy1;
        int x0 = (int)x0f, y0 = (int)y0f;
        int x1 = x0 + 1,   y1 = y0 + 1;

        float m00 = (x0>=0 && x0<WW && y0>=0 && y0<HH) ? 1.f : 0.f;
        float m10 = (x1>=0 && x1<WW && y0>=0 && y0<HH) ? 1.f : 0.f;
        float m01 = (x0>=0 && x0<WW && y1>=0 && y1<HH) ? 1.f : 0.f;
        float m11 = (x1>=0 && x1<WW && y1>=0 && y1<HH) ? 1.f : 0.f;
        float w00 = wx0*wy0*m00, w10 = wx1*wy0*m10;
        float w01 = wx0*wy1*m01, w11 = wx1*wy1*m11;

        int cx0 = min(max(x0,0),WW-1), cx1 = min(max(x1,0),WW-1);
        int cy0 = min(max(y0,0),HH-1), cy1 = min(max(y1,0),HH-1);
        int i00 = cy0*WW+cx0, i10 = cy0*WW+cx1;
        int i01 = cy1*WW+cx0, i11 = cy1*WW+cx1;

        float dot = 0.f, nrm = 0.f;
        const float* basep = srcp + (size_t)v*CC*HWHW;
        #pragma unroll
        for (int c=0; c<CC; c++) {
            const float* pc = basep + (size_t)c*HWHW;
            float wcv = w00*pc[i00] + w10*pc[i10] + w01*pc[i01] + w11*pc[i11];
            dot += rf[c]*wcv;
            nrm += wcv*wcv;
        }
        float sim = dot / fmaxf(sqrtf(nrm), 1e-12f);
        cost += valid ? sim : 0.f;
    }

    out[(size_t)d*HWHW + n] = cost * (1.0f/(float)VV);
    out[(size_t)NDB*HWHW + (size_t)d*HWHW + n] = depth;
}

extern "C" void kernel_launch(void* const* d_in, const int* in_sizes, int n_in,
                              void* d_out, int out_size, void* d_ws, size_t ws_size,
                              hipStream_t stream) {
    const float* ref_feat  = (const float*)d_in[0];
    const float* src_feats = (const float*)d_in[1];
    const float* K_ref     = (const float*)d_in[2];
    const float* c2w_ref   = (const float*)d_in[3];
    const float* K_srcs    = (const float*)d_in[4];
    const float* c2w_srcs  = (const float*)d_in[5];
    float* out = (float*)d_out;
    float* ws  = (float*)d_ws;

    size_t need_bytes = (size_t)CONST_FLOATS*sizeof(float)
                      + (size_t)(VV+1)*HWHW*CC*sizeof(_Float16);

    if (ws_size >= need_bytes) {
        _Float16* srcT = (_Float16*)(ws + CONST_FLOATS);
        _Float16* refT = srcT + (size_t)VV*HWHW*CC;
        int prep_threads = (VV+1)*HWHW + NDB*HWHW;
        prepass<<<(prep_threads + 255)/256, 256, 0, stream>>>(
            src_feats, ref_feat, K_ref, c2w_ref, K_srcs, c2w_srcs, srcT, refT, ws, out);
        // 320 strips x 16 depth-pairs, XCD-swizzled
        cost_volume_quad<<<(HWHW/64)*(NDB/2), 256, 0, stream>>>(srcT, refT, ws, out);
    } else {
        prepass<<<1, 1, 0, stream>>>(
            src_feats, ref_feat, K_ref, c2w_ref, K_srcs, c2w_srcs,
            (_Float16*)ws, (_Float16*)ws, ws, out);  // only gid==0 setup matters
        dim3 grid(HWHW/256, NDB);
        cost_volume_fallback<<<grid, 256, 0, stream>>>(src_feats, ref_feat, ws, out);
    }
}